// Round 9
// baseline (249.595 us; speedup 1.0000x reference)
//
#include <hip/hip_runtime.h>

#define RAD 6
#define KS 13
#define DIM 192
#define CH 3
#define W4C 48                  // float4 per row
#define PLANE4 (DIM * W4C)      // f4 per d-plane
#define VOL4 (DIM * PLANE4)     // f4 per channel
#define TOTAL (CH * DIM * DIM * DIM)

// ---------------- fused kernel geometry ----------------
#define WCH 2                   // output f4 cols per block
#define NWT (W4C / WCH)         // 24 w-tiles
#define DT 16                   // output depths per block
#define NDT (DIM / DT)          // 12
#define NSTEP (DT + 2 * RAD)    // 28 planes streamed (14 fat-steps)
#define NTF 384                 // 192 rows x 2 cols
#define GRIDF (CH * NWT * NDT)  // 864 = 8 * 108
#define WROWS (DIM + 2 * RAD)   // 204 wcb rows (6 zero-pad each end)
#define NBUF 4                  // wcb ring depth (1 barrier per 2 planes)

// Extract 1D gaussian: g3[i][j][k] = g1[i]*g1[j]*g1[k], sum(g1)=1 -> row-sum recovers g1.
__global__ void g1_extract_kernel(const float* __restrict__ w, float* __restrict__ g1) {
    int i = threadIdx.x;
    if (i < KS) {
        float s = 0.f;
        for (int j = 0; j < KS * KS; ++j) s += w[i * KS * KS + j];
        g1[i] = s;
    }
}

// ---------------------------------------------------------------------------
// Full-H column block, FAT steps: 2 planes per barrier, 4-deep wcb ring.
// Per fat-step f (planes s=2f, 2f+1):
//   W(s):   mask+shfl_xor w-window from PA regs -> 13-tap conv -> wcb[s&3];
//           then reissue PA <- plane s+2 (loads in flight across barrier)
//   W(s+1): same with PB; reissue PB <- plane s+3
//   lgkmcnt(0) + raw s_barrier  (no vmcnt drain)
//   H(s)+D(s), H(s+1)+D(s+1): 13 LDS taps each, D register window, store
// Ring safety: W(s+4) (fat f+2) reuses H(s)'s buffer (fat f) across the
// fat f+1 barrier. Halves barrier count and gives the scheduler two
// independent W chains / two H chains per phase to overlap VALU with LDS.
// ---------------------------------------------------------------------------
__global__ __launch_bounds__(NTF, 4) void conv3d_fused(const float* __restrict__ in,
                                                       float* __restrict__ out,
                                                       const float* __restrict__ g1v) {
    __shared__ float4 wcb[NBUF * WROWS * WCH];

    int bid = blockIdx.x;
    // bijective XCD swizzle: 864 = 8 * 108
    bid = (bid & 7) * (GRIDF / 8) + (bid >> 3);
    const int wt = bid % NWT;
    const int dt = (bid / NWT) % NDT;
    const int c  = bid / (NWT * NDT);
    const int d0 = dt * DT;
    const int t  = threadIdx.x;
    const int row = t >> 1;
    const int cw  = t & 1;

    float g[KS];
#pragma unroll
    for (int k = 0; k < KS; ++k) g[k] = g1v[k];

    const float4* __restrict__ in4 = (const float4*)in;
    float4* __restrict__ out4 = (float4*)out;
    const float4 z4 = make_float4(0.f, 0.f, 0.f, 0.f);

    // staged cols: local col = 2*i + cw; global f4 col = wt*2 - 2 + local
    int sOff[3]; float sm[3];
#pragma unroll
    for (int i = 0; i < 3; ++i) {
        int col = wt * WCH - 2 + 2 * i + cw;
        int colc = min(max(col, 0), W4C - 1);
        sOff[i] = c * VOL4 + row * W4C + colc;        // + dp*PLANE4 per step
        sm[i] = (col >= 0 && col < W4C) ? 1.f : 0.f;  // w zero-pad
    }
    const int wcbW = (row + RAD) * WCH + cw;          // write slot
    const int wcbR = row * WCH + cw;                  // read base (+k*WCH)
    const int outB = c * VOL4 + row * W4C + wt * WCH + cw;

    // zero the h-pad rows (0..5, 198..203) of all NBUF buffers
    if (t < NBUF * 2 * RAD * WCH) {                   // 96 threads
        int b  = t / (2 * RAD * WCH);
        int q  = t % (2 * RAD * WCH);
        int pr = q >> 1;
        int pc = q & 1;
        int r  = (pr < RAD) ? pr : (DIM + pr);        // 0..5 / 198..203
        wcb[b * WROWS * WCH + r * WCH + pc] = z4;
    }

    float4 wd[14];
#pragma unroll
    for (int j = 0; j < 14; ++j) wd[j] = z4;

    float4 pA0 = z4, pA1 = z4, pA2 = z4, pB0 = z4, pB1 = z4, pB2 = z4;
    {   // prologue: planes d0-6 (s=0) -> PA, d0-5 (s=1) -> PB
        const int dpa = d0 - RAD;
        if (dpa >= 0) {
            const int pb = dpa * PLANE4;
            pA0 = in4[pb + sOff[0]]; pA1 = in4[pb + sOff[1]]; pA2 = in4[pb + sOff[2]];
        }
        const int dpb = d0 - RAD + 1;
        if (dpb >= 0) {
            const int pb = dpb * PLANE4;
            pB0 = in4[pb + sOff[0]]; pB1 = in4[pb + sOff[1]]; pB2 = in4[pb + sOff[2]];
        }
    }
    __syncthreads();   // pad zeros visible (once; full drain fine here)

// ---- W phase for plane S using regs P0..P2; then reissue P <- plane S+2 ----
#define W_PHASE(S, P0, P1, P2)                                                    \
    {                                                                             \
        const int s_ = (S);                                                       \
        const int dp_ = d0 - RAD + s_;                                            \
        const bool dpv_ = (dp_ >= 0) && (dp_ < DIM);   /* block-uniform */        \
        const int bo_ = (s_ & 3) * (WROWS * WCH);                                 \
        float4 m0 = P0, m1 = P1, m2 = P2;              /* frees P for reissue */  \
        const int sp_ = s_ + 2;                                                   \
        const int dpp_ = d0 - RAD + sp_;                                          \
        if (sp_ < NSTEP && dpp_ >= 0 && dpp_ < DIM) {  /* prefetch plane s+2 */   \
            const int pb_ = dpp_ * PLANE4;                                        \
            P0 = in4[pb_ + sOff[0]];                                              \
            P1 = in4[pb_ + sOff[1]];                                              \
            P2 = in4[pb_ + sOff[2]];                                              \
        }                                                                         \
        if (dpv_) {                                                               \
            m0.x *= sm[0]; m0.y *= sm[0]; m0.z *= sm[0]; m0.w *= sm[0];           \
            m1.x *= sm[1]; m1.y *= sm[1]; m1.z *= sm[1]; m1.w *= sm[1];           \
            m2.x *= sm[2]; m2.y *= sm[2]; m2.z *= sm[2]; m2.w *= sm[2];           \
            float4 t0, t1, t2;                         /* row-sibling exchange */ \
            t0.x = __shfl_xor(m0.x, 1); t0.y = __shfl_xor(m0.y, 1);               \
            t0.z = __shfl_xor(m0.z, 1); t0.w = __shfl_xor(m0.w, 1);               \
            t1.x = __shfl_xor(m1.x, 1); t1.y = __shfl_xor(m1.y, 1);               \
            t1.z = __shfl_xor(m1.z, 1); t1.w = __shfl_xor(m1.w, 1);               \
            t2.x = __shfl_xor(m2.x, 1); t2.y = __shfl_xor(m2.y, 1);               \
            t2.z = __shfl_xor(m2.z, 1); t2.w = __shfl_xor(m2.w, 1);               \
            const float4 Fb = cw ? t1 : t0;                                       \
            const float4 Fd = cw ? t2 : t1;                                       \
            float F[20];                                                          \
            F[0]=m0.x; F[1]=m0.y; F[2]=m0.z; F[3]=m0.w;                           \
            F[4]=Fb.x; F[5]=Fb.y; F[6]=Fb.z; F[7]=Fb.w;                           \
            F[8]=m1.x; F[9]=m1.y; F[10]=m1.z; F[11]=m1.w;                         \
            F[12]=Fd.x; F[13]=Fd.y; F[14]=Fd.z; F[15]=Fd.w;                       \
            F[16]=m2.x; F[17]=m2.y; F[18]=m2.z; F[19]=m2.w;                       \
            float ax=0.f, ay=0.f, az=0.f, aw=0.f;                                 \
            _Pragma("unroll")                                                     \
            for (int k = 0; k < KS; ++k) {                                        \
                const float gw = g[k];                                            \
                ax += gw * F[k + 2]; ay += gw * F[k + 3];                         \
                az += gw * F[k + 4]; aw += gw * F[k + 5];                         \
            }                                                                     \
            wcb[bo_ + wcbW] = make_float4(ax, ay, az, aw);                        \
        }                                                                         \
    }

// ---- H + D phase for plane S (window slot OFF = S&1) ----
#define HD_PHASE(S, OFF)                                                          \
    {                                                                             \
        const int s_ = (S);                                                       \
        const int dp_ = d0 - RAD + s_;                                            \
        const bool dpv_ = (dp_ >= 0) && (dp_ < DIM);                              \
        const int bo_ = (s_ & 3) * (WROWS * WCH);                                 \
        float4 wh = z4;                                                           \
        if (dpv_) {                                                               \
            _Pragma("unroll")                                                     \
            for (int k = 0; k < KS; ++k) {                                        \
                const float4 T = wcb[bo_ + wcbR + k * WCH];                       \
                const float gw = g[k];                                            \
                wh.x += gw * T.x; wh.y += gw * T.y;                               \
                wh.z += gw * T.z; wh.w += gw * T.w;                               \
            }                                                                     \
        }                                                                         \
        wd[12 + (OFF)] = wh;                                                      \
        if (s_ >= 2 * RAD) {                                                      \
            const int o_ = d0 + s_ - 2 * RAD;                                     \
            float4 A = z4;                                                        \
            _Pragma("unroll")                                                     \
            for (int j = 0; j < KS; ++j) {                                        \
                const float gw = g[j];                                            \
                const float4 v = wd[j + (OFF)];                                   \
                A.x += gw * v.x; A.y += gw * v.y;                                 \
                A.z += gw * v.z; A.w += gw * v.w;                                 \
            }                                                                     \
            out4[outB + o_ * PLANE4] = A;                                         \
        }                                                                         \
    }

#pragma unroll 1
    for (int s2 = 0; s2 < NSTEP; s2 += 2) {
        W_PHASE(s2,     pA0, pA1, pA2)
        W_PHASE(s2 + 1, pB0, pB1, pB2)
        // LDS visibility only; prefetch loads stay in flight across barrier
        asm volatile("s_waitcnt lgkmcnt(0)" ::: "memory");
        __builtin_amdgcn_s_barrier();
        asm volatile("" ::: "memory");
        HD_PHASE(s2, 0)
        HD_PHASE(s2 + 1, 1)
#pragma unroll
        for (int j = 0; j < 12; ++j) wd[j] = wd[j + 2];   // pair shift
    }
#undef W_PHASE
#undef HD_PHASE
}

// Fallback: direct 2197-tap depthwise conv (only if ws_size is too small).
__global__ void naive_conv3d_kernel(const float* __restrict__ x, const float* __restrict__ w,
                                    float* __restrict__ out, int total) {
    int n = blockIdx.x * blockDim.x + threadIdx.x;
    if (n >= total) return;
    int wp = n % DIM;
    int h = (n / DIM) % DIM;
    int d = (n / (DIM * DIM)) % DIM;
    int c = n / (DIM * DIM * DIM);
    const float* wc = w + c * KS * KS * KS;
    const float* xc = x + (size_t)c * DIM * DIM * DIM;
    float acc = 0.f;
    for (int kd = 0; kd < KS; ++kd) {
        int dd = d + kd - RAD;
        if (dd < 0 || dd >= DIM) continue;
        for (int kh = 0; kh < KS; ++kh) {
            int hh = h + kh - RAD;
            if (hh < 0 || hh >= DIM) continue;
            for (int kw = 0; kw < KS; ++kw) {
                int ww = wp + kw - RAD;
                if (ww < 0 || ww >= DIM) continue;
                acc += wc[(kd * KS + kh) * KS + kw] * xc[((size_t)dd * DIM + hh) * DIM + ww];
            }
        }
    }
    out[n] = acc;
}

extern "C" void kernel_launch(void* const* d_in, const int* in_sizes, int n_in,
                              void* d_out, int out_size, void* d_ws, size_t ws_size,
                              hipStream_t stream) {
    const float* x = (const float*)d_in[0];
    const float* w = (const float*)d_in[1];
    float* out = (float*)d_out;

    if (ws_size >= 64) {
        float* g1 = (float*)d_ws;
        g1_extract_kernel<<<1, 64, 0, stream>>>(w, g1);
        conv3d_fused<<<GRIDF, NTF, 0, stream>>>(x, out, g1);
    } else {
        const int threads = 256;
        const int blocks = (TOTAL + threads - 1) / threads;
        naive_conv3d_kernel<<<blocks, threads, 0, stream>>>(x, w, out, TOTAL);
    }
}